// Round 6
// baseline (251.167 us; speedup 1.0000x reference)
//
#include <hip/hip_runtime.h>

typedef float v4 __attribute__((ext_vector_type(4)));
typedef float v2 __attribute__((ext_vector_type(2)));

#define D_MODEL 1024
#define D_STATE 64
#define CHUNK   256
#define TILE_T  64

// Grid: 512 blocks = 64 bc-chunks x 8 d-slices (128 d each). Block 256 thr =
// 4 waves -> 2 blocks/CU (128 KB LDS), 8 waves/CU, 2 waves/SIMD.
// Thread: ng = tid&7 owns n in [ng*8, ng*8+8); dp = tid>>3 owns 4 consecutive
// d = dsl*128 + dp*4. h,a: 8 x v4 in VGPRs (d_t=4).
// KEY INVARIANT (R2/R5): LDS instrs/CU/t = 128/d_t (n-split doesn't change it,
// a wave's ds_read is 1 instruction). d_t=4 -> 32 instrs/CU/t (~384 cyc), now
// UNDER the ~460 cyc/SIMD VALU term. n_t=8 keeps 256 thr/block -> 2 waves/SIMD.
// Reduction over 8 n-groups all on VALU: quad_perm xor1+xor2, then row_shl:4
// (lane i <- lane i+4; valid for writer lanes tid&7==0, which pull their own
// dp's other quad). Zero LDS-pipe reduction ops, zero per-t barriers.
template <int CTRL>
__device__ __forceinline__ float dpp_add(float v) {
    int p = __builtin_amdgcn_update_dpp(
        0, __builtin_bit_cast(int, v), CTRL, 0xF, 0xF, true);
    return v + __builtin_bit_cast(float, p);
}

__global__ __launch_bounds__(256, 2)
void YvParallelScan_kernel(const float* __restrict__ u,
                           const float* __restrict__ B,
                           const float* __restrict__ C,
                           const float* __restrict__ A_log,
                           float* __restrict__ out) {
    __shared__ v4 sB[2][TILE_T * 16];   // [buf][tl][n/4]  16 KB each
    __shared__ v4 sC[2][TILE_T * 16];

    const int bid = blockIdx.x;
    const int bc  = bid >> 3;          // 0..63  (batch*chunk index)
    const int dsl = bid & 7;           // d-slice (128 d each)
    const int tid = threadIdx.x;
    const int ng  = tid & 7;           // n-group of 8 (lanes 8k..8k+7)
    const int dp  = tid >> 3;          // 0..31: d-quad within slice
    const int d   = dsl * 128 + dp * 4;
    const int rowbase = bc * CHUNK;

    v4 a4[8], h4[8];
#pragma unroll
    for (int j = 0; j < 8; ++j) {
        const int n = ng * 8 + j;
        v4 al = *(const v4*)(A_log + (size_t)n * D_MODEL + d);
        v4 na;
        na[0] = -__expf(al[0]); na[1] = -__expf(al[1]);
        na[2] = -__expf(al[2]); na[3] = -__expf(al[3]);
        a4[j] = na;
        v4 z = {0.f, 0.f, 0.f, 0.f};
        h4[j] = z;
    }

    const v4* Bg = (const v4*)(B + (size_t)rowbase * D_STATE);
    const v4* Cg = (const v4*)(C + (size_t)rowbase * D_STATE);
    const float* uptr = u   + (size_t)rowbase * D_MODEL + d;
    float*       optr = out + (size_t)rowbase * D_MODEL + d;

    // prologue: stage tile 0 into buf 0 (4 v4 per thread per array)
    v4 rb[4], rc[4];
#pragma unroll
    for (int k = 0; k < 4; ++k) {
        rb[k] = Bg[k * 256 + tid];
        rc[k] = Cg[k * 256 + tid];
    }
#pragma unroll
    for (int k = 0; k < 4; ++k) {
        sB[0][k * 256 + tid] = rb[k];
        sC[0][k * 256 + tid] = rc[k];
    }

    // x prefetch depth 2
    v4 x0 = *(const v4*)(uptr);
    v4 x1 = *(const v4*)(uptr + D_MODEL);

    __syncthreads();

    for (int ti = 0; ti < CHUNK / TILE_T; ++ti) {
        const int cur = ti & 1;

        // issue next tile's global loads early (stall at most once per 64 t)
        if (ti < CHUNK / TILE_T - 1) {
#pragma unroll
            for (int k = 0; k < 4; ++k) {
                rb[k] = Bg[(ti + 1) * 1024 + k * 256 + tid];
                rc[k] = Cg[(ti + 1) * 1024 + k * 256 + tid];
            }
        }

#pragma unroll 4
        for (int tl = 0; tl < TILE_T; ++tl) {
            const int t  = ti * TILE_T + tl;
            const int tp = (t + 2 < CHUNK) ? t + 2 : CHUNK - 1;
            const v4 xn = *(const v4*)(uptr + (size_t)tp * D_MODEL);

            // 4 broadcast ds_read_b128: B,C slices for this thread's 8 n
            const v4 b0 = sB[cur][tl * 16 + ng * 2 + 0];
            const v4 b1 = sB[cur][tl * 16 + ng * 2 + 1];
            const v4 c0 = sC[cur][tl * 16 + ng * 2 + 0];
            const v4 c1 = sC[cur][tl * 16 + ng * 2 + 1];

            v4 accA = {0.f, 0.f, 0.f, 0.f};
            v4 accB = {0.f, 0.f, 0.f, 0.f};
#pragma unroll
            for (int j = 0; j < 4; ++j) {
                h4[j] = a4[j] * h4[j] + b0[j] * x0;
                accA += c0[j] * h4[j];
                h4[j + 4] = a4[j + 4] * h4[j + 4] + b1[j] * x0;
                accB += c1[j] * h4[j + 4];
            }
            v4 acc = accA + accB;

            // 8-lane n-reduction on the VALU pipe (per v4 component):
            // xor1, xor2 within quad, then row_shl:4 pulls the other quad.
#pragma unroll
            for (int kcomp = 0; kcomp < 4; ++kcomp) {
                float s = acc[kcomp];
                s = dpp_add<0xB1>(s);    // quad_perm [1,0,3,2]  (xor 1)
                s = dpp_add<0x4E>(s);    // quad_perm [2,3,0,1]  (xor 2)
                s = dpp_add<0x104>(s);   // row_shl:4 (lane i <- i+4)
                acc[kcomp] = s;
            }
            if (ng == 0) {
                *(v4*)(optr + (size_t)t * D_MODEL) = acc;  // dwordx4, coalesced
            }
            x0 = x1; x1 = xn;
        }

        // write next tile into the other buffer; single barrier per tile
        if (ti < CHUNK / TILE_T - 1) {
#pragma unroll
            for (int k = 0; k < 4; ++k) {
                sB[cur ^ 1][k * 256 + tid] = rb[k];
                sC[cur ^ 1][k * 256 + tid] = rc[k];
            }
        }
        __syncthreads();
    }
}

extern "C" void kernel_launch(void* const* d_in, const int* in_sizes, int n_in,
                              void* d_out, int out_size, void* d_ws, size_t ws_size,
                              hipStream_t stream) {
    const float* u     = (const float*)d_in[0];
    // d_in[1] = delta, unused by the reference forward
    const float* B     = (const float*)d_in[2];
    const float* C     = (const float*)d_in[3];
    const float* A_log = (const float*)d_in[4];
    float* out = (float*)d_out;

    YvParallelScan_kernel<<<512, 256, 0, stream>>>(u, B, C, A_log, out);
}